// Round 1
// baseline (803.154 us; speedup 1.0000x reference)
//
#include <hip/hip_runtime.h>
#include <stdint.h>

#define NF    1008
#define KP1   1024
#define NH1   256
#define NH2   192
#define NH3   160
#define MT    64
#define CELU_ALPHA 0.1f

typedef __attribute__((ext_vector_type(8))) __bf16 bf16x8;
typedef __attribute__((ext_vector_type(4))) float  f32x4;

// ws layout (bytes)
#define W1T_OFF   0u           // bf16 [5][256][1024] = 2,621,440
#define W2T_OFF   2621440u     // bf16 [5][192][256]  =   491,520
#define W3T_OFF   3112960u     // bf16 [5][160][192]  =   307,200
#define META_OFF  3420160u     // ints: counts[5]@0, atom_base[6]@8, tile_base[6]@16, cursors[5]@24
#define SORT_OFF  3420288u     // int [100000]

__device__ __forceinline__ unsigned short f2bf(float f) {
  union { float f; uint32_t u; } v; v.f = f;
  uint32_t u = v.u;
  uint32_t r = u + 0x7FFFu + ((u >> 16) & 1u);   // round-to-nearest-even
  return (unsigned short)(r >> 16);
}

__device__ __forceinline__ float celu_f(float x) {
  return x > 0.f ? x : CELU_ALPHA * (__expf(x * (1.f / CELU_ALPHA)) - 1.f);
}

__device__ __forceinline__ int ztype(int z) {
  // ELEMS = [1,6,7,8,9]
  return z == 1 ? 0 : z == 6 ? 1 : z == 7 ? 2 : z == 8 ? 3 : 4;
}

// ---------------- preprocessing ----------------

// Transpose+convert W -> bf16 [t][n][k], K zero-padded to KP (W1 only).
__global__ void prep_weights(const float* __restrict__ W1, const float* __restrict__ W2,
                             const float* __restrict__ W3,
                             unsigned short* __restrict__ w1t, unsigned short* __restrict__ w2t,
                             unsigned short* __restrict__ w3t) {
  int bid = blockIdx.x;
  const float* src; unsigned short* dst; int K, N, KP, kt, nt;
  if (bid < 320) {              // W1: 16x4 tiles x 5 types
    int t = bid / 64, r = bid % 64; kt = r / 4; nt = r % 4;
    src = W1 + (size_t)t * NF * NH1; dst = w1t + (size_t)t * NH1 * KP1;
    K = NF; N = NH1; KP = KP1;
  } else if (bid < 380) {       // W2: 4x3 tiles x 5 types
    int b = bid - 320; int t = b / 12, r = b % 12; kt = r / 3; nt = r % 3;
    src = W2 + (size_t)t * NH1 * NH2; dst = w2t + (size_t)t * NH2 * NH1;
    K = NH1; N = NH2; KP = NH1;
  } else {                      // W3: 3x3 tiles x 5 types
    int b = bid - 380; int t = b / 9, r = b % 9; kt = r / 3; nt = r % 3;
    src = W3 + (size_t)t * NH2 * NH3; dst = w3t + (size_t)t * NH3 * NH2;
    K = NH2; N = NH3; KP = NH2;
  }
  __shared__ float tile[64][65];
  int k0 = kt * 64, n0 = nt * 64;
  int tid = threadIdx.x;
  {
    int nl = tid & 63, kb = tid >> 6;
    #pragma unroll
    for (int i = 0; i < 16; ++i) {
      int kl = kb + 4 * i;
      int k = k0 + kl, n = n0 + nl;
      tile[kl][nl] = (k < K && n < N) ? src[(size_t)k * N + n] : 0.f;
    }
  }
  __syncthreads();
  {
    int klw = tid & 63, nb = tid >> 6;
    #pragma unroll
    for (int i = 0; i < 16; ++i) {
      int nl = nb + 4 * i;
      int n = n0 + nl, k = k0 + klw;
      if (n < N && k < KP) dst[(size_t)n * KP + k] = f2bf(tile[klw][nl]);
    }
  }
}

__global__ void hist_types(const int* __restrict__ z, int n, int* __restrict__ counts) {
  __shared__ int h[5];
  if (threadIdx.x < 5) h[threadIdx.x] = 0;
  __syncthreads();
  int i = blockIdx.x * blockDim.x + threadIdx.x;
  if (i < n) atomicAdd(&h[ztype(z[i])], 1);
  __syncthreads();
  if (threadIdx.x < 5 && h[threadIdx.x]) atomicAdd(&counts[threadIdx.x], h[threadIdx.x]);
}

__global__ void plan_tiles(const int* __restrict__ counts, int* __restrict__ atom_base,
                           int* __restrict__ tile_base) {
  if (threadIdx.x == 0 && blockIdx.x == 0) {
    int a = 0, tb = 0;
    for (int t = 0; t < 5; ++t) {
      atom_base[t] = a; tile_base[t] = tb;
      a += counts[t]; tb += (counts[t] + MT - 1) / MT;
    }
    atom_base[5] = a; tile_base[5] = tb;
  }
}

__global__ void scatter_atoms(const int* __restrict__ z, int n,
                              const int* __restrict__ atom_base, int* __restrict__ cursors,
                              int* __restrict__ sorted) {
  int i = blockIdx.x * blockDim.x + threadIdx.x;
  int lane = threadIdx.x & 63;
  int t = (i < n) ? ztype(z[i]) : -1;
  #pragma unroll
  for (int tt = 0; tt < 5; ++tt) {
    unsigned long long mask = __ballot(t == tt);
    if (t == tt) {
      int leader = __ffsll((long long)mask) - 1;
      int rank = __popcll(mask & ((1ull << lane) - 1ull));
      int base = 0;
      if (lane == leader) base = atomicAdd(&cursors[tt], (int)__popcll(mask));
      base = __shfl(base, leader);
      sorted[atom_base[tt] + base + rank] = i;
    }
  }
}

// ---------------- fused MLP ----------------
// One block = 64 atoms of a single element type. 4 waves; wave w owns n-tiles j%4==w.
// LDS: [0,25600): A-stage dbuf (2x64x72 bf16) in L1, then h2 (64x200 bf16).
//      [25600,59392): h1 (64x264 bf16) in L1/L2, then h3 (64x168 bf16).
//      [59392,59648): lgid[64].
__global__ __launch_bounds__(256, 2) void fcnn_main(
    const float* __restrict__ feat, const int* __restrict__ batch,
    const unsigned short* __restrict__ w1t, const unsigned short* __restrict__ w2t,
    const unsigned short* __restrict__ w3t, const float* __restrict__ W4,
    const float* __restrict__ b1, const float* __restrict__ b2,
    const float* __restrict__ b3, const float* __restrict__ b4,
    const int* __restrict__ atom_base, const int* __restrict__ tile_base,
    const int* __restrict__ sorted_idx, float* __restrict__ out) {
  __shared__ __align__(16) unsigned char smem[59648];
  unsigned short* Abuf = (unsigned short*)smem;             // [2][64][72]
  unsigned short* h2s  = (unsigned short*)smem;             // [64][200]
  unsigned short* h1s  = (unsigned short*)(smem + 25600);   // [64][264]
  unsigned short* h3s  = (unsigned short*)(smem + 25600);   // [64][168]
  int* lgid = (int*)(smem + 59392);

  const int bid = blockIdx.x;
  if (bid >= tile_base[5]) return;
  int t = 0;
  #pragma unroll
  for (int i = 0; i < 4; ++i) if (bid >= tile_base[i + 1]) t = i + 1;
  const int m0 = atom_base[t] + (bid - tile_base[t]) * MT;
  const int rows = min(MT, atom_base[t + 1] - m0);

  const int tid = threadIdx.x;
  const int lane = tid & 63;
  const int w = tid >> 6;
  const int col = lane & 15;
  const int q = lane >> 4;

  if (tid < MT) lgid[tid] = (tid < rows) ? sorted_idx[m0 + tid] : -1;
  __syncthreads();

  // ---- Layer 1: h1[64,256] = celu(A[64,1024] x W1t + b1), K chunks of 64
  const int srow = tid >> 2;
  const int sc4 = tid & 3;
  const int sg = lgid[srow];
  const float* fsrc = (sg >= 0) ? (feat + (size_t)sg * NF) : feat;
  const unsigned short* w1p = w1t + (size_t)t * NH1 * KP1;

  f32x4 acc[4][4];
  #pragma unroll
  for (int a = 0; a < 4; ++a)
    #pragma unroll
    for (int b = 0; b < 4; ++b) acc[a][b] = (f32x4){0.f, 0.f, 0.f, 0.f};

  f32x4 sv[4];
  #pragma unroll
  for (int i = 0; i < 4; ++i) {
    int c = sc4 + 4 * i;
    int k = c * 4;
    sv[i] = (sg >= 0 && k < NF) ? *(const f32x4*)(fsrc + k) : (f32x4){0.f, 0.f, 0.f, 0.f};
  }
  {
    unsigned short* dst = Abuf;
    #pragma unroll
    for (int i = 0; i < 4; ++i) {
      int c = sc4 + 4 * i;
      ushort4 pk;
      pk.x = f2bf(sv[i][0]); pk.y = f2bf(sv[i][1]); pk.z = f2bf(sv[i][2]); pk.w = f2bf(sv[i][3]);
      *(ushort4*)(dst + srow * 72 + c * 4) = pk;
    }
  }
  __syncthreads();

  #pragma unroll 1
  for (int kc = 0; kc < 16; ++kc) {
    const int cur = kc & 1;
    f32x4 nv[4];
    if (kc < 15) {
      #pragma unroll
      for (int i = 0; i < 4; ++i) {
        int c = sc4 + 4 * i;
        int k = (kc + 1) * 64 + c * 4;
        nv[i] = (sg >= 0 && k < NF) ? *(const f32x4*)(fsrc + k) : (f32x4){0.f, 0.f, 0.f, 0.f};
      }
    }
    const unsigned short* ab = Abuf + cur * 4608;
    #pragma unroll
    for (int ks = 0; ks < 2; ++ks) {
      bf16x8 af[4];
      #pragma unroll
      for (int im = 0; im < 4; ++im)
        af[im] = *(const bf16x8*)(ab + (im * 16 + col) * 72 + ks * 32 + q * 8);
      #pragma unroll
      for (int jj = 0; jj < 4; ++jj) {
        int n = (w + 4 * jj) * 16 + col;
        bf16x8 bfr = *(const bf16x8*)(w1p + (size_t)n * KP1 + kc * 64 + ks * 32 + q * 8);
        #pragma unroll
        for (int im = 0; im < 4; ++im)
          acc[im][jj] = __builtin_amdgcn_mfma_f32_16x16x32_bf16(af[im], bfr, acc[im][jj], 0, 0, 0);
      }
    }
    if (kc < 15) {
      unsigned short* dst = Abuf + (cur ^ 1) * 4608;
      #pragma unroll
      for (int i = 0; i < 4; ++i) {
        int c = sc4 + 4 * i;
        ushort4 pk;
        pk.x = f2bf(nv[i][0]); pk.y = f2bf(nv[i][1]); pk.z = f2bf(nv[i][2]); pk.w = f2bf(nv[i][3]);
        *(ushort4*)(dst + srow * 72 + c * 4) = pk;
      }
    }
    __syncthreads();
  }

  // epilogue L1 -> h1 (stride 264)
  #pragma unroll
  for (int jj = 0; jj < 4; ++jj) {
    int n = (w + 4 * jj) * 16 + col;
    float bias = b1[t * NH1 + n];
    #pragma unroll
    for (int im = 0; im < 4; ++im)
      #pragma unroll
      for (int r = 0; r < 4; ++r)
        h1s[(im * 16 + q * 4 + r) * 264 + n] = f2bf(celu_f(acc[im][jj][r] + bias));
  }
  __syncthreads();

  // ---- Layer 2: h2[64,192] = celu(h1 x W2t + b2), K=256
  f32x4 acc2[4][3];
  #pragma unroll
  for (int a = 0; a < 4; ++a)
    #pragma unroll
    for (int b = 0; b < 3; ++b) acc2[a][b] = (f32x4){0.f, 0.f, 0.f, 0.f};
  const unsigned short* w2p = w2t + (size_t)t * NH2 * NH1;
  #pragma unroll
  for (int ks = 0; ks < 8; ++ks) {
    bf16x8 af[4];
    #pragma unroll
    for (int im = 0; im < 4; ++im)
      af[im] = *(const bf16x8*)(h1s + (im * 16 + col) * 264 + ks * 32 + q * 8);
    #pragma unroll
    for (int jj = 0; jj < 3; ++jj) {
      int n = (w + 4 * jj) * 16 + col;
      bf16x8 bfr = *(const bf16x8*)(w2p + (size_t)n * NH1 + ks * 32 + q * 8);
      #pragma unroll
      for (int im = 0; im < 4; ++im)
        acc2[im][jj] = __builtin_amdgcn_mfma_f32_16x16x32_bf16(af[im], bfr, acc2[im][jj], 0, 0, 0);
    }
  }
  #pragma unroll
  for (int jj = 0; jj < 3; ++jj) {
    int n = (w + 4 * jj) * 16 + col;
    float bias = b2[t * NH2 + n];
    #pragma unroll
    for (int im = 0; im < 4; ++im)
      #pragma unroll
      for (int r = 0; r < 4; ++r)
        h2s[(im * 16 + q * 4 + r) * 200 + n] = f2bf(celu_f(acc2[im][jj][r] + bias));
  }
  __syncthreads();

  // ---- Layer 3: h3[64,160] = celu(h2 x W3t + b3), K=192
  f32x4 acc3[4][3];
  #pragma unroll
  for (int a = 0; a < 4; ++a)
    #pragma unroll
    for (int b = 0; b < 3; ++b) acc3[a][b] = (f32x4){0.f, 0.f, 0.f, 0.f};
  const unsigned short* w3p = w3t + (size_t)t * NH3 * NH2;
  #pragma unroll
  for (int ks = 0; ks < 6; ++ks) {
    bf16x8 af[4];
    #pragma unroll
    for (int im = 0; im < 4; ++im)
      af[im] = *(const bf16x8*)(h2s + (im * 16 + col) * 200 + ks * 32 + q * 8);
    #pragma unroll
    for (int jj = 0; jj < 3; ++jj) {
      int j = w + 4 * jj;
      if (j < 10) {
        int n = j * 16 + col;
        bf16x8 bfr = *(const bf16x8*)(w3p + (size_t)n * NH2 + ks * 32 + q * 8);
        #pragma unroll
        for (int im = 0; im < 4; ++im)
          acc3[im][jj] = __builtin_amdgcn_mfma_f32_16x16x32_bf16(af[im], bfr, acc3[im][jj], 0, 0, 0);
      }
    }
  }
  #pragma unroll
  for (int jj = 0; jj < 3; ++jj) {
    int j = w + 4 * jj;
    if (j < 10) {
      int n = j * 16 + col;
      float bias = b3[t * NH3 + n];
      #pragma unroll
      for (int im = 0; im < 4; ++im)
        #pragma unroll
        for (int r = 0; r < 4; ++r)
          h3s[(im * 16 + q * 4 + r) * 168 + n] = f2bf(celu_f(acc3[im][jj][r] + bias));
    }
  }
  __syncthreads();

  // ---- Layer 4: v = h3 . W4[t] + b4[t]; atomicAdd into molecule
  {
    int a = tid >> 2, p = tid & 3;
    float v = 0.f;
    if (a < rows) {
      const float* wp = W4 + t * NH3;
      #pragma unroll
      for (int c0 = 0; c0 < 5; ++c0) {
        int c = p + 4 * c0;   // 0..19 chunks of 8
        bf16x8 hv = *(const bf16x8*)(h3s + a * 168 + c * 8);
        #pragma unroll
        for (int j = 0; j < 8; ++j) v += (float)hv[j] * wp[c * 8 + j];
      }
    }
    v += __shfl_xor(v, 1);
    v += __shfl_xor(v, 2);
    if (p == 0 && a < rows) {
      int g = lgid[a];
      atomicAdd(&out[batch[g]], v + b4[t]);
    }
  }
}

// ---------------- launch ----------------
extern "C" void kernel_launch(void* const* d_in, const int* in_sizes, int n_in,
                              void* d_out, int out_size, void* d_ws, size_t ws_size,
                              hipStream_t stream) {
  const int*   z    = (const int*)d_in[0];
  const float* feat = (const float*)d_in[1];
  const int*   bat  = (const int*)d_in[2];
  const float* W1 = (const float*)d_in[4];
  const float* b1 = (const float*)d_in[5];
  const float* W2 = (const float*)d_in[6];
  const float* b2 = (const float*)d_in[7];
  const float* W3 = (const float*)d_in[8];
  const float* b3 = (const float*)d_in[9];
  const float* W4 = (const float*)d_in[10];
  const float* b4 = (const float*)d_in[11];
  const int n = in_sizes[0];

  unsigned char* ws = (unsigned char*)d_ws;
  unsigned short* w1t = (unsigned short*)(ws + W1T_OFF);
  unsigned short* w2t = (unsigned short*)(ws + W2T_OFF);
  unsigned short* w3t = (unsigned short*)(ws + W3T_OFF);
  int* meta = (int*)(ws + META_OFF);
  int* counts    = meta;
  int* atom_base = meta + 8;
  int* tile_base = meta + 16;
  int* cursors   = meta + 24;
  int* sorted    = (int*)(ws + SORT_OFF);

  hipMemsetAsync(meta, 0, 128, stream);
  hipMemsetAsync(d_out, 0, (size_t)out_size * sizeof(float), stream);

  prep_weights<<<425, 256, 0, stream>>>(W1, W2, W3, w1t, w2t, w3t);
  int nb = (n + 255) / 256;
  hist_types<<<nb, 256, 0, stream>>>(z, n, counts);
  plan_tiles<<<1, 64, 0, stream>>>(counts, atom_base, tile_base);
  scatter_atoms<<<nb, 256, 0, stream>>>(z, n, atom_base, cursors, sorted);
  int max_tiles = n / MT + 6;
  fcnn_main<<<max_tiles, 256, 0, stream>>>(feat, bat, w1t, w2t, w3t, W4,
                                           b1, b2, b3, b4,
                                           atom_base, tile_base, sorted,
                                           (float*)d_out);
  (void)n_in; (void)ws_size;
}

// Round 2
// 783.785 us; speedup vs baseline: 1.0247x; 1.0247x over previous
//
#include <hip/hip_runtime.h>
#include <stdint.h>

#define NF    1008
#define KP1   1024
#define NH1   256
#define NH2   192
#define NH3   160
#define MT    64
#define CELU_ALPHA 0.1f

typedef __attribute__((ext_vector_type(8))) __bf16 bf16x8;
typedef __attribute__((ext_vector_type(4))) float  f32x4;

// ws layout (bytes)
#define W1T_OFF   0u           // bf16 [5][256][1024] = 2,621,440
#define W2T_OFF   2621440u     // bf16 [5][192][256]  =   491,520
#define W3T_OFF   3112960u     // bf16 [5][160][192]  =   307,200
#define META_OFF  3420160u     // ints: counts[5]@0, atom_base[6]@8, tile_base[6]@16, cursors[5]@24
#define SORT_OFF  3420288u     // int [100000]

__device__ __forceinline__ unsigned short f2bf(float f) {
  union { float f; uint32_t u; } v; v.f = f;
  uint32_t u = v.u;
  uint32_t r = u + 0x7FFFu + ((u >> 16) & 1u);   // round-to-nearest-even
  return (unsigned short)(r >> 16);
}

__device__ __forceinline__ float celu_f(float x) {
  return x > 0.f ? x : CELU_ALPHA * (__expf(x * (1.f / CELU_ALPHA)) - 1.f);
}

__device__ __forceinline__ int ztype(int z) {
  return z == 1 ? 0 : z == 6 ? 1 : z == 7 ? 2 : z == 8 ? 3 : 4;
}

// ---------------- preprocessing ----------------
// blocks [0,425): transpose+convert weights -> bf16 [t][n][k] (K1 padded to 1024)
// blocks [425, 425+nb): per-type histogram of z
__global__ void prep_and_hist(const float* __restrict__ W1, const float* __restrict__ W2,
                              const float* __restrict__ W3,
                              unsigned short* __restrict__ w1t, unsigned short* __restrict__ w2t,
                              unsigned short* __restrict__ w3t,
                              const int* __restrict__ z, int n, int* __restrict__ counts) {
  int bid = blockIdx.x;
  int tid = threadIdx.x;
  if (bid >= 425) {
    __shared__ int h[5];
    if (tid < 5) h[tid] = 0;
    __syncthreads();
    int i = (bid - 425) * 256 + tid;
    if (i < n) atomicAdd(&h[ztype(z[i])], 1);
    __syncthreads();
    if (tid < 5 && h[tid]) atomicAdd(&counts[tid], h[tid]);
    return;
  }
  const float* src; unsigned short* dst; int K, N, KP, kt, nt;
  if (bid < 320) {              // W1: 16x4 tiles x 5 types
    int t = bid / 64, r = bid % 64; kt = r / 4; nt = r % 4;
    src = W1 + (size_t)t * NF * NH1; dst = w1t + (size_t)t * NH1 * KP1;
    K = NF; N = NH1; KP = KP1;
  } else if (bid < 380) {       // W2: 4x3 tiles x 5 types
    int b = bid - 320; int t = b / 12, r = b % 12; kt = r / 3; nt = r % 3;
    src = W2 + (size_t)t * NH1 * NH2; dst = w2t + (size_t)t * NH2 * NH1;
    K = NH1; N = NH2; KP = NH1;
  } else {                      // W3: 3x3 tiles x 5 types
    int b = bid - 380; int t = b / 9, r = b % 9; kt = r / 3; nt = r % 3;
    src = W3 + (size_t)t * NH2 * NH3; dst = w3t + (size_t)t * NH3 * NH2;
    K = NH2; N = NH3; KP = NH2;
  }
  __shared__ float tile[64][65];
  int k0 = kt * 64, n0 = nt * 64;
  {
    int nl = tid & 63, kb = tid >> 6;
    #pragma unroll
    for (int i = 0; i < 16; ++i) {
      int kl = kb + 4 * i;
      int k = k0 + kl, nn = n0 + nl;
      tile[kl][nl] = (k < K && nn < N) ? src[(size_t)k * N + nn] : 0.f;
    }
  }
  __syncthreads();
  {
    int klw = tid & 63, nb2 = tid >> 6;
    #pragma unroll
    for (int i = 0; i < 16; ++i) {
      int nl = nb2 + 4 * i;
      int nn = n0 + nl, k = k0 + klw;
      if (nn < N && k < KP) dst[(size_t)nn * KP + k] = f2bf(tile[klw][nl]);
    }
  }
}

__global__ void plan_tiles(const int* __restrict__ counts, int* __restrict__ atom_base,
                           int* __restrict__ tile_base) {
  if (threadIdx.x == 0 && blockIdx.x == 0) {
    int a = 0, tb = 0;
    for (int t = 0; t < 5; ++t) {
      atom_base[t] = a; tile_base[t] = tb;
      a += counts[t]; tb += (counts[t] + MT - 1) / MT;
    }
    atom_base[5] = a; tile_base[5] = tb;
  }
}

__global__ void scatter_atoms(const int* __restrict__ z, int n,
                              const int* __restrict__ atom_base, int* __restrict__ cursors,
                              int* __restrict__ sorted) {
  int i = blockIdx.x * blockDim.x + threadIdx.x;
  int lane = threadIdx.x & 63;
  int t = (i < n) ? ztype(z[i]) : -1;
  #pragma unroll
  for (int tt = 0; tt < 5; ++tt) {
    unsigned long long mask = __ballot(t == tt);
    if (t == tt) {
      int leader = __ffsll((long long)mask) - 1;
      int rank = __popcll(mask & ((1ull << lane) - 1ull));
      int base = 0;
      if (lane == leader) base = atomicAdd(&cursors[tt], (int)__popcll(mask));
      base = __shfl(base, leader);
      sorted[atom_base[tt] + base + rank] = i;
    }
  }
}

// ---------------- fused MLP ----------------
// One block = 64 atoms of one type, 8 waves (512 thr). Wave w owns n-tiles j = w + 8*jj.
// LDS regions (67,840 B total -> 2 blocks/CU, 16 waves/CU):
//   A dbuf: A0 [0,33792) + A1 [33792,67584), each 64 x 264 bf16 (K-chunk 256 + pad 8)
//   h1 [0,33792) stride 264 (overlaps A0; A0 dead after K-loop)
//   h2 [33792,59392) stride 200 (overlaps A1; A1 dead after K-loop)
//   h3 [0,21504) stride 168 (overlaps h1; h1 dead after L2 MFMAs + barrier)
//   lgid [67584,67840)
__global__ __launch_bounds__(512, 4) void fcnn_main(
    const float* __restrict__ feat, const int* __restrict__ batch,
    const unsigned short* __restrict__ w1t, const unsigned short* __restrict__ w2t,
    const unsigned short* __restrict__ w3t, const float* __restrict__ W4,
    const float* __restrict__ b1, const float* __restrict__ b2,
    const float* __restrict__ b3, const float* __restrict__ b4,
    const int* __restrict__ atom_base, const int* __restrict__ tile_base,
    const int* __restrict__ sorted_idx, float* __restrict__ out) {
  __shared__ __align__(16) unsigned char smem[67840];
  unsigned short* A0  = (unsigned short*)smem;
  unsigned short* A1  = (unsigned short*)(smem + 33792);
  unsigned short* h1s = (unsigned short*)smem;
  unsigned short* h2s = (unsigned short*)(smem + 33792);
  unsigned short* h3s = (unsigned short*)smem;
  int* lgid = (int*)(smem + 67584);

  const int bid = blockIdx.x;
  if (bid >= tile_base[5]) return;
  int t = 0;
  #pragma unroll
  for (int i = 0; i < 4; ++i) if (bid >= tile_base[i + 1]) t = i + 1;
  const int m0 = atom_base[t] + (bid - tile_base[t]) * MT;
  const int rows = min(MT, atom_base[t + 1] - m0);

  const int tid = threadIdx.x;
  const int lane = tid & 63;
  const int w = tid >> 6;          // 0..7
  const int col = lane & 15;
  const int q = lane >> 4;

  if (tid < MT) lgid[tid] = (tid < rows) ? sorted_idx[m0 + tid] : -1;
  __syncthreads();

  // ---- Layer 1: h1[64,256] = celu(A[64,1024] x W1t + b1), 4 K-chunks of 256
  const int srow = tid >> 3;       // 0..63
  const int sl = tid & 7;
  const int sg = lgid[srow];
  const float* fsrc = (sg >= 0) ? (feat + (size_t)sg * NF) : feat;
  const unsigned short* w1p = w1t + (size_t)t * NH1 * KP1;

  f32x4 acc[4][2];
  #pragma unroll
  for (int a = 0; a < 4; ++a)
    #pragma unroll
    for (int b = 0; b < 2; ++b) acc[a][b] = (f32x4){0.f, 0.f, 0.f, 0.f};

  f32x4 nv[8];
  #pragma unroll
  for (int i = 0; i < 8; ++i) {
    int k = (sl + 8 * i) * 4;
    nv[i] = (sg >= 0 && k < NF) ? *(const f32x4*)(fsrc + k) : (f32x4){0.f, 0.f, 0.f, 0.f};
  }
  #pragma unroll
  for (int i = 0; i < 8; ++i) {
    int c = sl + 8 * i;
    ushort4 pk;
    pk.x = f2bf(nv[i][0]); pk.y = f2bf(nv[i][1]); pk.z = f2bf(nv[i][2]); pk.w = f2bf(nv[i][3]);
    *(ushort4*)(A0 + srow * 264 + c * 4) = pk;
  }
  __syncthreads();

  #pragma unroll 1
  for (int kc = 0; kc < 4; ++kc) {
    if (kc < 3) {
      #pragma unroll
      for (int i = 0; i < 8; ++i) {
        int k = (kc + 1) * 256 + (sl + 8 * i) * 4;
        nv[i] = (sg >= 0 && k < NF) ? *(const f32x4*)(fsrc + k) : (f32x4){0.f, 0.f, 0.f, 0.f};
      }
    }
    const unsigned short* ab = (kc & 1) ? A1 : A0;
    #pragma unroll
    for (int ks = 0; ks < 8; ++ks) {
      bf16x8 af[4];
      #pragma unroll
      for (int im = 0; im < 4; ++im)
        af[im] = *(const bf16x8*)(ab + (im * 16 + col) * 264 + ks * 32 + q * 8);
      #pragma unroll
      for (int jj = 0; jj < 2; ++jj) {
        int n = (w + 8 * jj) * 16 + col;
        bf16x8 bfr = *(const bf16x8*)(w1p + (size_t)n * KP1 + kc * 256 + ks * 32 + q * 8);
        #pragma unroll
        for (int im = 0; im < 4; ++im)
          acc[im][jj] = __builtin_amdgcn_mfma_f32_16x16x32_bf16(af[im], bfr, acc[im][jj], 0, 0, 0);
      }
    }
    if (kc < 3) {
      unsigned short* dst = (kc & 1) ? A0 : A1;   // buffer (kc+1)&1
      #pragma unroll
      for (int i = 0; i < 8; ++i) {
        int c = sl + 8 * i;
        ushort4 pk;
        pk.x = f2bf(nv[i][0]); pk.y = f2bf(nv[i][1]); pk.z = f2bf(nv[i][2]); pk.w = f2bf(nv[i][3]);
        *(ushort4*)(dst + srow * 264 + c * 4) = pk;
      }
    }
    __syncthreads();
  }

  // epilogue L1 -> h1 (stride 264, overlaps dead A0)
  #pragma unroll
  for (int jj = 0; jj < 2; ++jj) {
    int n = (w + 8 * jj) * 16 + col;
    float bias = b1[t * NH1 + n];
    #pragma unroll
    for (int im = 0; im < 4; ++im)
      #pragma unroll
      for (int r = 0; r < 4; ++r)
        h1s[(im * 16 + q * 4 + r) * 264 + n] = f2bf(celu_f(acc[im][jj][r] + bias));
  }
  __syncthreads();

  // ---- Layer 2: h2[64,192] = celu(h1 x W2t + b2), K=256, 12 n-tiles
  f32x4 acc2[4][2];
  #pragma unroll
  for (int a = 0; a < 4; ++a)
    #pragma unroll
    for (int b = 0; b < 2; ++b) acc2[a][b] = (f32x4){0.f, 0.f, 0.f, 0.f};
  const unsigned short* w2p = w2t + (size_t)t * NH2 * NH1;
  #pragma unroll
  for (int ks = 0; ks < 8; ++ks) {
    bf16x8 af[4];
    #pragma unroll
    for (int im = 0; im < 4; ++im)
      af[im] = *(const bf16x8*)(h1s + (im * 16 + col) * 264 + ks * 32 + q * 8);
    #pragma unroll
    for (int jj = 0; jj < 2; ++jj) {
      int j = w + 8 * jj;
      if (j < 12) {
        int n = j * 16 + col;
        bf16x8 bfr = *(const bf16x8*)(w2p + (size_t)n * NH1 + ks * 32 + q * 8);
        #pragma unroll
        for (int im = 0; im < 4; ++im)
          acc2[im][jj] = __builtin_amdgcn_mfma_f32_16x16x32_bf16(af[im], bfr, acc2[im][jj], 0, 0, 0);
      }
    }
  }
  #pragma unroll
  for (int jj = 0; jj < 2; ++jj) {
    int j = w + 8 * jj;
    if (j < 12) {
      int n = j * 16 + col;
      float bias = b2[t * NH2 + n];
      #pragma unroll
      for (int im = 0; im < 4; ++im)
        #pragma unroll
        for (int r = 0; r < 4; ++r)
          h2s[(im * 16 + q * 4 + r) * 200 + n] = f2bf(celu_f(acc2[im][jj][r] + bias));
    }
  }
  __syncthreads();

  // ---- Layer 3: h3[64,160] = celu(h2 x W3t + b3), K=192, 10 n-tiles
  f32x4 acc3[4][2];
  #pragma unroll
  for (int a = 0; a < 4; ++a)
    #pragma unroll
    for (int b = 0; b < 2; ++b) acc3[a][b] = (f32x4){0.f, 0.f, 0.f, 0.f};
  const unsigned short* w3p = w3t + (size_t)t * NH3 * NH2;
  #pragma unroll
  for (int ks = 0; ks < 6; ++ks) {
    bf16x8 af[4];
    #pragma unroll
    for (int im = 0; im < 4; ++im)
      af[im] = *(const bf16x8*)(h2s + (im * 16 + col) * 200 + ks * 32 + q * 8);
    #pragma unroll
    for (int jj = 0; jj < 2; ++jj) {
      int j = w + 8 * jj;
      if (j < 10) {
        int n = j * 16 + col;
        bf16x8 bfr = *(const bf16x8*)(w3p + (size_t)n * NH2 + ks * 32 + q * 8);
        #pragma unroll
        for (int im = 0; im < 4; ++im)
          acc3[im][jj] = __builtin_amdgcn_mfma_f32_16x16x32_bf16(af[im], bfr, acc3[im][jj], 0, 0, 0);
      }
    }
  }
  #pragma unroll
  for (int jj = 0; jj < 2; ++jj) {
    int j = w + 8 * jj;
    if (j < 10) {
      int n = j * 16 + col;
      float bias = b3[t * NH3 + n];
      #pragma unroll
      for (int im = 0; im < 4; ++im)
        #pragma unroll
        for (int r = 0; r < 4; ++r)
          h3s[(im * 16 + q * 4 + r) * 168 + n] = f2bf(celu_f(acc3[im][jj][r] + bias));
    }
  }
  __syncthreads();

  // ---- Layer 4: v = h3 . W4[t] + b4[t]; atomicAdd into molecule
  {
    int a = tid >> 3, p = tid & 7;
    float v = 0.f;
    if (a < rows) {
      const float* wp = W4 + t * NH3;
      #pragma unroll
      for (int c0 = 0; c0 < 3; ++c0) {
        int c = p + 8 * c0;   // 20 chunks of 8 elems
        if (c < 20) {
          bf16x8 hv = *(const bf16x8*)(h3s + a * 168 + c * 8);
          #pragma unroll
          for (int j = 0; j < 8; ++j) v += (float)hv[j] * wp[c * 8 + j];
        }
      }
    }
    v += __shfl_xor(v, 1);
    v += __shfl_xor(v, 2);
    v += __shfl_xor(v, 4);
    if (p == 0 && a < rows) {
      int g = lgid[a];
      atomicAdd(&out[batch[g]], v + b4[t]);
    }
  }
}

// ---------------- launch ----------------
extern "C" void kernel_launch(void* const* d_in, const int* in_sizes, int n_in,
                              void* d_out, int out_size, void* d_ws, size_t ws_size,
                              hipStream_t stream) {
  const int*   z    = (const int*)d_in[0];
  const float* feat = (const float*)d_in[1];
  const int*   bat  = (const int*)d_in[2];
  const float* W1 = (const float*)d_in[4];
  const float* b1 = (const float*)d_in[5];
  const float* W2 = (const float*)d_in[6];
  const float* b2 = (const float*)d_in[7];
  const float* W3 = (const float*)d_in[8];
  const float* b3 = (const float*)d_in[9];
  const float* W4 = (const float*)d_in[10];
  const float* b4 = (const float*)d_in[11];
  const int n = in_sizes[0];

  unsigned char* ws = (unsigned char*)d_ws;
  unsigned short* w1t = (unsigned short*)(ws + W1T_OFF);
  unsigned short* w2t = (unsigned short*)(ws + W2T_OFF);
  unsigned short* w3t = (unsigned short*)(ws + W3T_OFF);
  int* meta = (int*)(ws + META_OFF);
  int* counts    = meta;
  int* atom_base = meta + 8;
  int* tile_base = meta + 16;
  int* cursors   = meta + 24;
  int* sorted    = (int*)(ws + SORT_OFF);

  hipMemsetAsync(meta, 0, 128, stream);
  hipMemsetAsync(d_out, 0, (size_t)out_size * sizeof(float), stream);

  int nb = (n + 255) / 256;
  prep_and_hist<<<425 + nb, 256, 0, stream>>>(W1, W2, W3, w1t, w2t, w3t, z, n, counts);
  plan_tiles<<<1, 64, 0, stream>>>(counts, atom_base, tile_base);
  scatter_atoms<<<nb, 256, 0, stream>>>(z, n, atom_base, cursors, sorted);
  int max_tiles = n / MT + 6;
  fcnn_main<<<max_tiles, 512, 0, stream>>>(feat, bat, w1t, w2t, w3t, W4,
                                           b1, b2, b3, b4,
                                           atom_base, tile_base, sorted,
                                           (float*)d_out);
  (void)n_in; (void)ws_size;
}